// Round 15
// baseline (250.832 us; speedup 1.0000x reference)
//
#include <hip/hip_runtime.h>
#include <hip/hip_bf16.h>

typedef _Float16 f16;
typedef f16  f16x4 __attribute__((ext_vector_type(4)));
typedef f16  f16x8 __attribute__((ext_vector_type(8)));
typedef float f32x4 __attribute__((ext_vector_type(4)));
typedef float f32x16 __attribute__((ext_vector_type(16)));

// ---------------- workspace layout ----------------
// Tpre : [256][26(c,i)][196p][8g] f16
// Wb2  : [13cg][13ky][13kx][64l][8] f16
// Wf1b : [33ks][26kstep][6nt][64l][8] f16
// Pp   : [2par][256b][7mt][32r][32o] f32
// h2f  : [256][1029] f32
// P3   : [33][256][89] f32
static constexpr size_t TP_OFF = 0;
static constexpr size_t TP_BYTES = (size_t)256 * 26 * 196 * 8 * 2;        // 20,873,216
static constexpr size_t WB_OFF = TP_OFF + TP_BYTES;
static constexpr size_t WB_BYTES = (size_t)2197 * 64 * 8 * 2;             // 2,249,728
static constexpr size_t WF_OFF = WB_OFF + WB_BYTES;
static constexpr size_t WF_BYTES = (size_t)33 * 26 * 6 * 64 * 8 * 2;      // 5,271,552
static constexpr size_t PP_OFF = WF_OFF + WF_BYTES;
static constexpr size_t PP_BYTES = (size_t)2 * 256 * 7 * 32 * 32 * 4;     // 14,680,064
static constexpr size_t H2_OFF = PP_OFF + PP_BYTES;
static constexpr size_t H2_BYTES = (size_t)256 * 1029 * 4;                // 1,053,696
static constexpr size_t P3_OFF = H2_OFF + H2_BYTES;

static constexpr int NCH = 33;

// ------------------------------------------------------------------
// K_front: merged prep_wb (553 blocks) + prep_wf (132) + conv1 (512).
// Independent work; merging overlaps what a single stream serializes.
// Shared 40KB LDS union.
// ------------------------------------------------------------------
__device__ __forceinline__ void prep_wb_body(const float* __restrict__ w2,
                                             f16* __restrict__ Wb2, int bid) {
    int idx = bid * 256 + threadIdx.x;   // 2197*64 = 140,608
    if (idx >= 2197 * 64) return;
    int l = idx & 63; int frag = idx >> 6;
    int kx = frag % 13; int t2 = frag / 13;
    int ky = t2 % 13; int cg = t2 / 13;
    int o = l & 31;
    f16x8 v;
#pragma unroll
    for (int i = 0; i < 8; ++i) {
        float wv = 0.f;
        if (o < 21) {
            int ch = cg * 16 + (l >> 5) * 8 + i;
            int c2 = ch / 104, rr = ch % 104, ii = rr >> 3, gg = rr & 7;
            wv = w2[(size_t)(c2 * 21 + o) * 17576 + ii * 1352 + ky * 104 + kx * 8 + gg];
        }
        v[i] = (f16)wv;
    }
    *(f16x8*)&Wb2[(size_t)idx * 8] = v;
}

__device__ __forceinline__ void prep_wf_body(char* smem,
                                             const float* __restrict__ wf1,
                                             f16* __restrict__ Wf1b, int sub) {
    // sub in [0,132): oseg = sub&1 (o 0..47 / 48..95), c = (sub>>1)&1, ks = sub>>2
    f16 (*Wl)[48 * 32] = (f16(*)[48 * 32])smem;   // [13][1536] = 39,936 B
    int oseg = sub & 1, c = (sub >> 1) & 1, ks = sub >> 2;
    int o0 = oseg * 48;
    int tid = threadIdx.x;
    for (int e = tid; e < 48 * 32; e += 256) {
        int orel = e >> 5, dl = e & 31;
        int o = o0 + orel, d = ks * 32 + dl;
        if (o < 89 && d < 1029) {
            const float* p = wf1 + ((size_t)(c * 89 + o) * 1029 + d) * 13;
#pragma unroll
            for (int g = 0; g < 13; ++g) Wl[g][e] = (f16)p[g];
        } else {
#pragma unroll
            for (int g = 0; g < 13; ++g) Wl[g][e] = (f16)0;
        }
    }
    __syncthreads();
    for (int t = tid; t < 48 * 13 * 4; t += 256) {
        int koct = t & 3; int q = t >> 2; int g = q % 13; int orel = q / 13;
        int o = o0 + orel;
        f16x8 v;
#pragma unroll
        for (int i = 0; i < 8; ++i) v[i] = Wl[g][orel * 32 + koct * 8 + i];
        int l = koct * 16 + (o & 15);
        int nt = o >> 4;
        *(f16x8*)&Wf1b[(((size_t)ks * 26 + c * 13 + g) * 6 + nt) * 512 + (size_t)l * 8] = v;
    }
}

__device__ __forceinline__ void conv1_body(char* smem,
                                           const float* __restrict__ x,
                                           const float* __restrict__ w1,
                                           const float* __restrict__ b1,
                                           f16* __restrict__ Tpre, int bid) {
    float2 (*tcs)[448] = (float2(*)[448])smem;                 // 17,920 B
    float*  cv = (float*)(smem + 17920);                       // 20,384 B
    float*  bl = (float*)(smem + 38304);                       // 52 B
    int tid = threadIdx.x;
    int b = bid >> 1, yh = bid & 1;
    int y0 = yh * 12;
    const float* xb = x + (size_t)b * 784;
    if (tid < 13) bl[tid] = b1[tid];
    for (int i = tid; i < 448; i += 256) {
        float v = xb[y0 * 28 + i];
        float s1, c1; __sincosf(v, &s1, &c1);
        float ck = c1, sk = s1, ckm = 1.f, skm = 0.f;
#pragma unroll
        for (int g = 0; g < 5; ++g) {
            tcs[g][i] = make_float2(ck, sk);
            float cn = 2.f * c1 * ck - ckm, sn = 2.f * c1 * sk - skm;
            ckm = ck; ck = cn; skm = sk; sk = sn;
        }
    }
    __syncthreads();
    for (int pp = tid; pp < 392; pp += 256) {
        int yl = pp / 28, xx = pp % 28;
        int y = yh * 14 + yl;
        float acc[13] = {};
        for (int ky = 0; ky < 5; ++ky) {
            int row = y + ky - 2;
            if ((unsigned)row >= 28u) continue;
            int lr = row - y0;
            for (int kx = 0; kx < 5; ++kx) {
                int col = xx + kx - 2;
                if ((unsigned)col >= 28u) continue;
                float2 tv[5];
#pragma unroll
                for (int g = 0; g < 5; ++g) tv[g] = tcs[g][lr * 28 + col];
#pragma unroll
                for (int o = 0; o < 13; ++o) {
                    const float* wco = w1 + (o * 25 + ky * 5 + kx) * 5;
                    const float* wso = wco + 1625;
                    float a = acc[o];
#pragma unroll
                    for (int g = 0; g < 5; ++g)
                        a = fmaf(tv[g].x, wco[g], fmaf(tv[g].y, wso[g], a));
                    acc[o] = a;
                }
            }
        }
#pragma unroll
        for (int o = 0; o < 13; ++o) cv[pp * 13 + o] = acc[o];
    }
    __syncthreads();
    for (int i = tid; i < 13 * 7 * 14; i += 256) {
        int o = i / 98; int rem = i % 98; int pyl = rem / 14; int px = rem % 14;
        int base0 = ((pyl * 2) * 28 + px * 2) * 13 + o;
        float m = fmaxf(fmaxf(cv[base0], cv[base0 + 13]),
                        fmaxf(cv[base0 + 28 * 13], cv[base0 + 28 * 13 + 13]));
        int p = (yh * 7 + pyl) * 14 + px;
        float h = m + bl[o];
        float s1, c1; __sincosf(h, &s1, &c1);
        f16x8 vc, vs;
        float ck = c1, sk = s1, ckm = 1.f, skm = 0.f;
#pragma unroll
        for (int g = 0; g < 8; ++g) {
            vc[g] = (f16)ck; vs[g] = (f16)sk;
            float cn = 2.f * c1 * ck - ckm, sn = 2.f * c1 * sk - skm;
            ckm = ck; ck = cn; skm = sk; sk = sn;
        }
        *(f16x8*)&Tpre[((size_t)(b * 26 + o) * 196 + p) * 8] = vc;
        *(f16x8*)&Tpre[((size_t)(b * 26 + 13 + o) * 196 + p) * 8] = vs;
    }
}

__global__ __launch_bounds__(256) void k_front(const float* __restrict__ x,
                                               const float* __restrict__ w1,
                                               const float* __restrict__ b1,
                                               const float* __restrict__ w2,
                                               const float* __restrict__ wf1,
                                               f16* __restrict__ Wb2,
                                               f16* __restrict__ Wf1b,
                                               f16* __restrict__ Tpre) {
    __shared__ __align__(16) char smem[40960];
    int bid = blockIdx.x;
    if (bid < 553)      prep_wb_body(w2, Wb2, bid);
    else if (bid < 685) prep_wf_body(smem, wf1, Wf1b, bid - 553);
    else                conv1_body(smem, x, w1, b1, Tpre, bid - 685);
}

// ------------------------------------------------------------------
// K2: conv2 mfma_32x32x16, round-13 parity structure (256,2) +
// register PREFETCH of next cg's Tpre (loads issued before the MFMA
// phase -> L2 latency hides under MFMA; staging becomes write-only).
// ------------------------------------------------------------------
template<int PAR>
__device__ __forceinline__ void conv2m_body(const f16* __restrict__ Tpre,
                                            const f16* __restrict__ Wb2,
                                            float* __restrict__ Pp,
                                            f16* Tl, int b) {
    const int tid = threadIdx.x;
    const int l = tid & 63, w = tid >> 6;
    const int oct = l >> 5;
    const int pyb = (l >> 4) & 1;
    const int px = l & 15;

    // zero halo once: cells (yy,oc,xx)
    for (int pos = tid; pos < 1792; pos += 256) {
        int yy2 = pos >> 5, xx = pos & 31;
        int yy = yy2 >> 1;
        if (yy < 6 || yy >= 20 || xx < 6 || xx >= 20) {
            f16x8 z = {};
            *(f16x8*)&Tl[(yy2 * 32 + xx) * 8] = z;
        }
    }

    // Tpre channel index for (cg, oc) is simply 2*cg+oc.
    auto ldT = [&](int cg, int j) -> f16x8 {
        int oc = (j >= 196), p = j - oc * 196;
        return *(const f16x8*)&Tpre[((size_t)(b * 26 + 2 * cg + oc) * 196 + p) * 8];
    };
    auto stT = [&](int j, f16x8 v) {
        int oc = (j >= 196), p = j - oc * 196;
        int y = p / 14, xp = p - y * 14;
        *(f16x8*)&Tl[((((y + 6) * 2 + oc) * 32) + xp + 6) * 8] = v;
    };

    f16x8 pr0 = ldT(0, tid);
    f16x8 pr1;
    if (tid < 136) pr1 = ldT(0, tid + 256);

    f32x16 acc[7] = {};

    for (int cg = 0; cg < 13; ++cg) {
        if (cg) __syncthreads();            // cg-1 MFMA reads done
        stT(tid, pr0);
        if (tid < 136) stT(tid + 256, pr1);
        __syncthreads();
        if (cg + 1 < 13) {                  // issue next-cg loads NOW
            pr0 = ldT(cg + 1, tid);
            if (tid < 136) pr1 = ldT(cg + 1, tid + 256);
        }

        const int j0 = (w + cg) & 3;
        for (int kxs = 0; kxs < 4; ++kxs) {
            const int kx = j0 + kxs * 4;
            if (kx > 12) break;             // uniform per wave
            f16x8 bf[7 - PAR];
#pragma unroll
            for (int t = 0; t < 7 - PAR; ++t) {
                int ky = PAR + 2 * t;
                bf[t] = *(const f16x8*)&Wb2[(((size_t)(cg * 13 + ky) * 13 + kx) * 64 + l) * 8];
            }
            const int xx = px + kx;
#pragma unroll
            for (int kp = 0; kp < 13 - PAR; ++kp) {
                const int yy = PAR + 2 * kp + pyb;
                f16x8 a = *(const f16x8*)&Tl[(((yy * 2 + oct) * 32) + xx) * 8];
#pragma unroll
                for (int t = 0; t < 7 - PAR; ++t) {
                    const int mt = kp - t;
                    if (mt >= 0 && mt <= 6)
                        acc[mt] = __builtin_amdgcn_mfma_f32_32x32x16_f16(a, bf[t], acc[mt], 0, 0, 0);
                }
            }
        }
    }

    // 4-wave LDS reduction into R[7][32][32] (reuses Tl)
    __syncthreads();
    float* R = (float*)Tl;
    for (int ph = 0; ph < 4; ++ph) {
        if (w == ph) {
#pragma unroll
            for (int mt = 0; mt < 7; ++mt)
#pragma unroll
                for (int reg = 0; reg < 16; ++reg) {
                    int row = (reg & 3) + 8 * (reg >> 2) + 4 * oct;
                    int idx = (mt * 32 + row) * 32 + (l & 31);
                    float v = acc[mt][reg];
                    if (ph) v += R[idx];
                    R[idx] = v;
                }
        }
        __syncthreads();
    }
    float* P = Pp + (size_t)(PAR * 256 + b) * 7168;
    for (int i = tid; i < 7168; i += 256) P[i] = R[i];
}

__global__ __launch_bounds__(256, 2) void k_conv2m(const f16* __restrict__ Tpre,
                                                   const f16* __restrict__ Wb2,
                                                   float* __restrict__ Pp) {
    __shared__ f16 Tl[28 * 2 * 32 * 8];   // 28,672 B
    int bid = blockIdx.x;
    int b = bid >> 1;
    if (bid & 1) conv2m_body<1>(Tpre, Wb2, Pp, Tl, b);
    else         conv2m_body<0>(Tpre, Wb2, Pp, Tl, b);
}

// ------------------------------------------------------------------
// K3: sum 2 parity partials + maxpool + bias -> h2f
// ------------------------------------------------------------------
__global__ __launch_bounds__(256) void k_pool2(const float* __restrict__ Pp,
                                               const float* __restrict__ b2,
                                               float* __restrict__ h2f) {
    int b = blockIdx.x, tid = threadIdx.x;
    for (int idx = tid; idx < 1029; idx += 256) {
        int o = idx % 21; int r = idx / 21; int px = r % 7; int py = r / 7;
        float mx = -1e30f;
#pragma unroll
        for (int sy = 0; sy < 2; ++sy)
#pragma unroll
            for (int sx = 0; sx < 2; ++sx) {
                int py2 = 2 * py + sy, px2 = 2 * px + sx;
                int mt = py2 >> 1, rr = (py2 & 1) * 16 + px2;
                float v = Pp[(size_t)b * 7168 + (mt * 32 + rr) * 32 + o]
                        + Pp[(size_t)(256 + b) * 7168 + (mt * 32 + rr) * 32 + o];
                mx = fmaxf(mx, v);
            }
        h2f[(size_t)b * 1029 + o * 49 + py * 7 + px] = mx + b2[o];
    }
}

// ------------------------------------------------------------------
// K4: fk1 via MFMA (b64 staging, unchanged from round 14).
// ------------------------------------------------------------------
__global__ __launch_bounds__(256) void k_fk1m(const float* __restrict__ h2f,
                                              const f16* __restrict__ Wf1b,
                                              float* __restrict__ P3) {
    __shared__ f16 A[26 * 32 * 32];
    const int bid = blockIdx.x;
    const int mt8 = bid / NCH, ks = bid % NCH;
    const int m0 = mt8 * 32, d0 = ks * 32;
    const int tid = threadIdx.x;
    {
        const int m = tid >> 3, dq = tid & 7;
        float c1v[4], s1v[4], ck[4], sk[4], ckm[4], skm[4];
        bool valid[4];
#pragma unroll
        for (int j = 0; j < 4; ++j) {
            int d = d0 + dq * 4 + j;
            valid[j] = d < 1029;
            float h = valid[j] ? h2f[(size_t)(m0 + m) * 1029 + d] : 0.f;
            float s1, c1; __sincosf(h, &s1, &c1);
            c1v[j] = c1; s1v[j] = s1;
            ck[j] = c1; sk[j] = s1; ckm[j] = 1.f; skm[j] = 0.f;
        }
#pragma unroll
        for (int g = 0; g < 13; ++g) {
            f16x4 vc, vs;
#pragma unroll
            for (int j = 0; j < 4; ++j) {
                vc[j] = valid[j] ? (f16)ck[j] : (f16)0;
                vs[j] = valid[j] ? (f16)sk[j] : (f16)0;
                float cn = 2.f * c1v[j] * ck[j] - ckm[j];
                float sn = 2.f * c1v[j] * sk[j] - skm[j];
                ckm[j] = ck[j]; ck[j] = cn; skm[j] = sk[j]; sk[j] = sn;
            }
            *(f16x4*)&A[g * 1024 + m * 32 + dq * 4] = vc;
            *(f16x4*)&A[(13 + g) * 1024 + m * 32 + dq * 4] = vs;
        }
    }
    __syncthreads();
    const int w = tid >> 6, l = tid & 63;
    const int mt = w >> 1, ntg = (w & 1) * 3;
    f32x4 acc[3] = {};
    for (int kstep = 0; kstep < 26; ++kstep) {
        f16x8 a = *(const f16x8*)&A[kstep * 1024 + (mt * 16 + (l & 15)) * 32 + (l >> 4) * 8];
#pragma unroll
        for (int j = 0; j < 3; ++j) {
            f16x8 bv = *(const f16x8*)&Wf1b[((((size_t)ks * 26 + kstep) * 6 + ntg + j) * 64 + l) * 8];
            acc[j] = __builtin_amdgcn_mfma_f32_16x16x32_f16(a, bv, acc[j], 0, 0, 0);
        }
    }
    const int o_base = (l & 15);
#pragma unroll
    for (int j = 0; j < 3; ++j) {
        int o = (ntg + j) * 16 + o_base;
        if (o < 89) {
#pragma unroll
            for (int jj = 0; jj < 4; ++jj) {
                int m = m0 + mt * 16 + (l >> 4) * 4 + jj;
                P3[((size_t)ks * 256 + m) * 89 + o] = acc[j][jj];
            }
        }
    }
}

// ------------------------------------------------------------------
// K5: reduce 33 fk1 partials + bias -> trig(G=8) -> fk2 -> f32 out
// ------------------------------------------------------------------
__global__ __launch_bounds__(128) void k_fk2(const float* __restrict__ P3,
                                             const float* __restrict__ bias1,
                                             const float* __restrict__ wf2,
                                             const float* __restrict__ bias2,
                                             float* __restrict__ out) {
    __shared__ float2 tcs2[89][8];
    __shared__ float part[80];
    int b = blockIdx.x, tid = threadIdx.x;
    if (tid < 89) {
        float v = bias1[tid];
        for (int ks = 0; ks < NCH; ++ks)
            v += P3[((size_t)ks * 256 + b) * 89 + tid];
#pragma unroll
        for (int g = 0; g < 8; ++g) {
            float s, c; __sincosf(v * (float)(g + 1), &s, &c);
            tcs2[tid][g] = make_float2(c, s);
        }
    }
    __syncthreads();
    if (tid < 80) {
        int o = tid >> 3, g = tid & 7;
        float s = 0.f;
        for (int d = 0; d < 89; ++d) {
            float2 tv = tcs2[d][g];
            s = fmaf(tv.x, wf2[((size_t)o * 89 + d) * 8 + g],
                fmaf(tv.y, wf2[7120 + ((size_t)o * 89 + d) * 8 + g], s));
        }
        part[tid] = s;
    }
    __syncthreads();
    if (tid < 10) {
        float v = bias2[tid];
#pragma unroll
        for (int g = 0; g < 8; ++g) v += part[tid * 8 + g];
        out[b * 10 + tid] = v;
    }
}

extern "C" void kernel_launch(void* const* d_in, const int* in_sizes, int n_in,
                              void* d_out, int out_size, void* d_ws, size_t ws_size,
                              hipStream_t stream) {
    const float* x   = (const float*)d_in[0];
    const float* w1  = (const float*)d_in[1];
    const float* b1  = (const float*)d_in[2];
    const float* w2  = (const float*)d_in[3];
    const float* b2  = (const float*)d_in[4];
    const float* wf1 = (const float*)d_in[5];
    const float* bf1 = (const float*)d_in[6];
    const float* wf2 = (const float*)d_in[7];
    const float* bf2v = (const float*)d_in[8];

    char* ws  = (char*)d_ws;
    f16*   Tpre = (f16*)(ws + TP_OFF);
    f16*   Wb2  = (f16*)(ws + WB_OFF);
    f16*   Wf1b = (f16*)(ws + WF_OFF);
    float* Pp   = (float*)(ws + PP_OFF);
    float* h2f  = (float*)(ws + H2_OFF);
    float* P3   = (float*)(ws + P3_OFF);

    k_front<<<1197, 256, 0, stream>>>(x, w1, b1, w2, wf1, Wb2, Wf1b, Tpre);
    k_conv2m<<<512, 256, 0, stream>>>(Tpre, Wb2, Pp);
    k_pool2<<<256, 256, 0, stream>>>(Pp, b2, h2f);
    k_fk1m<<<8 * NCH, 256, 0, stream>>>(h2f, Wf1b, P3);
    k_fk2<<<256, 128, 0, stream>>>(P3, bf1, wf2, bf2v, (float*)d_out);
}

// Round 16
// 177.307 us; speedup vs baseline: 1.4147x; 1.4147x over previous
//
#include <hip/hip_runtime.h>
#include <hip/hip_bf16.h>

typedef _Float16 f16;
typedef f16  f16x4 __attribute__((ext_vector_type(4)));
typedef f16  f16x8 __attribute__((ext_vector_type(8)));
typedef float f32x4 __attribute__((ext_vector_type(4)));
typedef float f32x16 __attribute__((ext_vector_type(16)));

// ---------------- workspace layout ----------------
// Tpre : [256][26(c,i)][196p][8g] f16
// Wb2  : [13cg][13ky][13kx][64l][8] f16
// Wf1b : [33ks][26kstep][6nt][64l][8] f16
// Wb1  : [39q][64l][8] f16   conv1 B-frags (3 hi/lo passes x 13 kc)
// Pp   : [2par][256b][7mt][32r][32o] f32
// h2f  : [256][1029] f32
// P3   : [33][256][89] f32
static constexpr size_t TP_OFF = 0;
static constexpr size_t TP_BYTES = (size_t)256 * 26 * 196 * 8 * 2;        // 20,873,216
static constexpr size_t WB_OFF = TP_OFF + TP_BYTES;
static constexpr size_t WB_BYTES = (size_t)2197 * 64 * 8 * 2;             // 2,249,728
static constexpr size_t WF_OFF = WB_OFF + WB_BYTES;
static constexpr size_t WF_BYTES = (size_t)33 * 26 * 6 * 64 * 8 * 2;      // 5,271,552
static constexpr size_t W1_OFF = WF_OFF + WF_BYTES;
static constexpr size_t W1_BYTES = (size_t)39 * 64 * 8 * 2;               // 39,936
static constexpr size_t PP_OFF = W1_OFF + ((W1_BYTES + 255) & ~size_t(255));
static constexpr size_t PP_BYTES = (size_t)2 * 256 * 7 * 32 * 32 * 4;     // 14,680,064
static constexpr size_t H2_OFF = PP_OFF + PP_BYTES;
static constexpr size_t H2_BYTES = (size_t)256 * 1029 * 4;                // 1,053,696
static constexpr size_t P3_OFF = H2_OFF + H2_BYTES;

static constexpr int NCH = 33;

// ------------------------------------------------------------------
// K_front bodies: prep_wb (553 blocks) + prep_wf (132) + prep_w1 (10).
// ------------------------------------------------------------------
__device__ __forceinline__ void prep_wb_body(const float* __restrict__ w2,
                                             f16* __restrict__ Wb2, int bid) {
    int idx = bid * 256 + threadIdx.x;   // 2197*64 = 140,608
    if (idx >= 2197 * 64) return;
    int l = idx & 63; int frag = idx >> 6;
    int kx = frag % 13; int t2 = frag / 13;
    int ky = t2 % 13; int cg = t2 / 13;
    int o = l & 31;
    f16x8 v;
#pragma unroll
    for (int i = 0; i < 8; ++i) {
        float wv = 0.f;
        if (o < 21) {
            int ch = cg * 16 + (l >> 5) * 8 + i;
            int c2 = ch / 104, rr = ch % 104, ii = rr >> 3, gg = rr & 7;
            wv = w2[(size_t)(c2 * 21 + o) * 17576 + ii * 1352 + ky * 104 + kx * 8 + gg];
        }
        v[i] = (f16)wv;
    }
    *(f16x8*)&Wb2[(size_t)idx * 8] = v;
}

__device__ __forceinline__ void prep_wf_body(char* smem,
                                             const float* __restrict__ wf1,
                                             f16* __restrict__ Wf1b, int sub) {
    f16 (*Wl)[48 * 32] = (f16(*)[48 * 32])smem;   // [13][1536] = 39,936 B
    int oseg = sub & 1, c = (sub >> 1) & 1, ks = sub >> 2;
    int o0 = oseg * 48;
    int tid = threadIdx.x;
    for (int e = tid; e < 48 * 32; e += 256) {
        int orel = e >> 5, dl = e & 31;
        int o = o0 + orel, d = ks * 32 + dl;
        if (o < 89 && d < 1029) {
            const float* p = wf1 + ((size_t)(c * 89 + o) * 1029 + d) * 13;
#pragma unroll
            for (int g = 0; g < 13; ++g) Wl[g][e] = (f16)p[g];
        } else {
#pragma unroll
            for (int g = 0; g < 13; ++g) Wl[g][e] = (f16)0;
        }
    }
    __syncthreads();
    for (int t = tid; t < 48 * 13 * 4; t += 256) {
        int koct = t & 3; int q = t >> 2; int g = q % 13; int orel = q / 13;
        int o = o0 + orel;
        f16x8 v;
#pragma unroll
        for (int i = 0; i < 8; ++i) v[i] = Wl[g][orel * 32 + koct * 8 + i];
        int l = koct * 16 + (o & 15);
        int nt = o >> 4;
        *(f16x8*)&Wf1b[(((size_t)ks * 26 + c * 13 + g) * 6 + nt) * 512 + (size_t)l * 8] = v;
    }
}

// conv1 B-frags: q = pass*13+kc (pass 0,1: hi; pass 2: lo); lane l:
// o = l&15, kk=(l>>4)*8+i: tap=2kc+(kk>>4), j=kk&15 (j<5: cos g=j,
// 5<=j<10: sin g=j-5, else 0); zero for tap>=25 or o>=13.
__device__ __forceinline__ void prep_w1_body(const float* __restrict__ w1,
                                             f16* __restrict__ Wb1, int sub) {
    int idx = sub * 256 + threadIdx.x;
    if (idx >= 39 * 64) return;
    int l = idx & 63; int q = idx >> 6;
    int pass = q / 13, kc = q % 13;
    int o = l & 15;
    f16x8 v;
#pragma unroll
    for (int i = 0; i < 8; ++i) {
        int kk = (l >> 4) * 8 + i;
        int tap = 2 * kc + (kk >> 4);
        int j = kk & 15;
        f16 out = (f16)0;
        if (tap < 25 && j < 10 && o < 13) {
            int c = j / 5, g = j % 5;
            int ky = tap / 5, kx = tap - 5 * ky;
            float wv = w1[c * 1625 + o * 125 + ky * 25 + kx * 5 + g];
            f16 hi = (f16)wv;
            out = (pass == 2) ? (f16)(wv - (float)hi) : hi;
        }
        v[i] = out;
    }
    *(f16x8*)&Wb1[(size_t)idx * 8] = v;
}

__global__ __launch_bounds__(256) void k_front(const float* __restrict__ w1,
                                               const float* __restrict__ w2,
                                               const float* __restrict__ wf1,
                                               f16* __restrict__ Wb2,
                                               f16* __restrict__ Wf1b,
                                               f16* __restrict__ Wb1) {
    __shared__ __align__(16) char smem[40960];
    int bid = blockIdx.x;
    if (bid < 553)      prep_wb_body(w2, Wb2, bid);
    else if (bid < 685) prep_wf_body(smem, wf1, Wf1b, bid - 553);
    else                prep_w1_body(w1, Wb1, bid - 685);
}

// ------------------------------------------------------------------
// K1: conv1 via MFMA (3-pass f16 hi/lo split for f32-grade accuracy).
// Block = (image, 7-row-pair half).  A = trig(G=5) staged in padded
// LDS [20 rows][32 cols][16 j] (hi+lo planes).  Per wave-pair: 4
// tiles (2 y x 2 x-half) x 39 K-chunks.  Pool 2x2 in-register
// (x-pairs in-lane j, y-pairs across acc tiles) -> +bias -> trig G=8
// -> Tpre.
// ------------------------------------------------------------------
__global__ __launch_bounds__(256) void k_conv1m(const float* __restrict__ x,
                                                const float* __restrict__ b1,
                                                const f16* __restrict__ Wb1,
                                                f16* __restrict__ Tpre) {
    __shared__ f16 tH[640 * 16];   // 20,480 B
    __shared__ f16 tL[640 * 16];   // 20,480 B
    __shared__ float bl[16];
    const int bid = blockIdx.x;
    const int b = bid >> 1, h2 = bid & 1;
    const int base = h2 * 14;      // output rows [base, base+14)
    const int tid = threadIdx.x;
    if (tid < 16) bl[tid] = (tid < 13) ? b1[tid] : 0.f;
    for (int i = tid; i < 640; i += 256) {
        f16x8 z = {};
        *(f16x8*)&tH[i * 16] = z; *(f16x8*)&tH[i * 16 + 8] = z;
        *(f16x8*)&tL[i * 16] = z; *(f16x8*)&tL[i * 16 + 8] = z;
    }
    __syncthreads();
    // stage input rows [base-2, base+18) -> local rows 0..19, cols +2
    for (int s = tid; s < 560; s += 256) {
        int r = s / 28, ix = s % 28;
        int iy = base + r - 2;
        if ((unsigned)iy < 28u) {
            float v = x[(size_t)b * 784 + iy * 28 + ix];
            float s1, c1; __sincosf(v, &s1, &c1);
            float cg[5], sg[5];
            float ck = c1, sk = s1, ckm = 1.f, skm = 0.f;
#pragma unroll
            for (int g = 0; g < 5; ++g) {
                cg[g] = ck; sg[g] = sk;
                float cn = 2.f * c1 * ck - ckm, sn = 2.f * c1 * sk - skm;
                ckm = ck; ck = cn; skm = sk; sk = sn;
            }
            f16x8 hA, hB = {}, lA, lB = {};
#pragma unroll
            for (int g = 0; g < 5; ++g) {
                f16 h = (f16)cg[g]; hA[g] = h; lA[g] = (f16)(cg[g] - (float)h);
            }
#pragma unroll
            for (int g = 0; g < 3; ++g) {
                f16 h = (f16)sg[g]; hA[5 + g] = h; lA[5 + g] = (f16)(sg[g] - (float)h);
            }
#pragma unroll
            for (int g = 3; g < 5; ++g) {
                f16 h = (f16)sg[g]; hB[g - 3] = h; lB[g - 3] = (f16)(sg[g] - (float)h);
            }
            int pos = r * 32 + ix + 2;
            *(f16x8*)&tH[pos * 16] = hA; *(f16x8*)&tH[pos * 16 + 8] = hB;
            *(f16x8*)&tL[pos * 16] = lA; *(f16x8*)&tL[pos * 16 + 8] = lB;
        }
    }
    __syncthreads();

    const int l = tid & 63, w = tid >> 6;
    const int col = l & 15, g4 = l >> 4;
    const int tof = g4 >> 1, jh = g4 & 1;
    for (int pi = 0; pi < 2; ++pi) {
        int pl = w + 4 * pi;
        if (pl >= 7) break;
        f32x4 acc[4] = {};   // [yy*2 + hh]
#pragma unroll 1
        for (int pass = 0; pass < 3; ++pass) {
            const f16* pa = (pass == 1) ? tL : tH;
#pragma unroll
            for (int kc = 0; kc < 13; ++kc) {
                f16x8 bf = *(const f16x8*)&Wb1[((size_t)(pass * 13 + kc) * 64 + l) * 8];
                int tap = 2 * kc + tof;            // <= 25; tap 25 has B==0
                int ky = tap / 5, kx = tap - 5 * ky;
#pragma unroll
                for (int yy = 0; yy < 2; ++yy)
#pragma unroll
                    for (int hh = 0; hh < 2; ++hh) {
                        int pos = (2 * pl + yy + ky) * 32 + hh * 14 + col + kx;
                        f16x8 a = *(const f16x8*)&pa[pos * 16 + jh * 8];
                        acc[yy * 2 + hh] = __builtin_amdgcn_mfma_f32_16x16x32_f16(a, bf, acc[yy * 2 + hh], 0, 0, 0);
                    }
            }
        }
        // pool 2x2: x-pairs in-lane (j 0/1, 2/3), y-pairs across acc tiles
        if (col < 13) {
            int gpy = h2 * 7 + pl;
#pragma unroll
            for (int hh = 0; hh < 2; ++hh)
#pragma unroll
                for (int jp = 0; jp < 2; ++jp) {
                    if (g4 == 3 && jp == 1) continue;       // x=14,15 / 28,29 dups
                    int px = hh * 7 + 2 * g4 + jp;
                    float m = fmaxf(fmaxf(acc[hh][2 * jp], acc[hh][2 * jp + 1]),
                                    fmaxf(acc[2 + hh][2 * jp], acc[2 + hh][2 * jp + 1]));
                    float hval = m + bl[col];
                    float s1, c1; __sincosf(hval, &s1, &c1);
                    f16x8 vc, vs;
                    float ck = c1, sk = s1, ckm = 1.f, skm = 0.f;
#pragma unroll
                    for (int g = 0; g < 8; ++g) {
                        vc[g] = (f16)ck; vs[g] = (f16)sk;
                        float cn = 2.f * c1 * ck - ckm, sn = 2.f * c1 * sk - skm;
                        ckm = ck; ck = cn; skm = sk; sk = sn;
                    }
                    int p = gpy * 14 + px;
                    *(f16x8*)&Tpre[((size_t)(b * 26 + col) * 196 + p) * 8] = vc;
                    *(f16x8*)&Tpre[((size_t)(b * 26 + 13 + col) * 196 + p) * 8] = vs;
                }
        }
    }
}

// ------------------------------------------------------------------
// K2: conv2 mfma_32x32x16, parity split + register prefetch
// (unchanged from round 15).
// ------------------------------------------------------------------
template<int PAR>
__device__ __forceinline__ void conv2m_body(const f16* __restrict__ Tpre,
                                            const f16* __restrict__ Wb2,
                                            float* __restrict__ Pp,
                                            f16* Tl, int b) {
    const int tid = threadIdx.x;
    const int l = tid & 63, w = tid >> 6;
    const int oct = l >> 5;
    const int pyb = (l >> 4) & 1;
    const int px = l & 15;

    for (int pos = tid; pos < 1792; pos += 256) {
        int yy2 = pos >> 5, xx = pos & 31;
        int yy = yy2 >> 1;
        if (yy < 6 || yy >= 20 || xx < 6 || xx >= 20) {
            f16x8 z = {};
            *(f16x8*)&Tl[(yy2 * 32 + xx) * 8] = z;
        }
    }

    auto ldT = [&](int cg, int j) -> f16x8 {
        int oc = (j >= 196), p = j - oc * 196;
        return *(const f16x8*)&Tpre[((size_t)(b * 26 + 2 * cg + oc) * 196 + p) * 8];
    };
    auto stT = [&](int j, f16x8 v) {
        int oc = (j >= 196), p = j - oc * 196;
        int y = p / 14, xp = p - y * 14;
        *(f16x8*)&Tl[((((y + 6) * 2 + oc) * 32) + xp + 6) * 8] = v;
    };

    f16x8 pr0 = ldT(0, tid);
    f16x8 pr1;
    if (tid < 136) pr1 = ldT(0, tid + 256);

    f32x16 acc[7] = {};

    for (int cg = 0; cg < 13; ++cg) {
        if (cg) __syncthreads();
        stT(tid, pr0);
        if (tid < 136) stT(tid + 256, pr1);
        __syncthreads();
        if (cg + 1 < 13) {
            pr0 = ldT(cg + 1, tid);
            if (tid < 136) pr1 = ldT(cg + 1, tid + 256);
        }

        const int j0 = (w + cg) & 3;
        for (int kxs = 0; kxs < 4; ++kxs) {
            const int kx = j0 + kxs * 4;
            if (kx > 12) break;
            f16x8 bf[7 - PAR];
#pragma unroll
            for (int t = 0; t < 7 - PAR; ++t) {
                int ky = PAR + 2 * t;
                bf[t] = *(const f16x8*)&Wb2[(((size_t)(cg * 13 + ky) * 13 + kx) * 64 + l) * 8];
            }
            const int xx = px + kx;
#pragma unroll
            for (int kp = 0; kp < 13 - PAR; ++kp) {
                const int yy = PAR + 2 * kp + pyb;
                f16x8 a = *(const f16x8*)&Tl[(((yy * 2 + oct) * 32) + xx) * 8];
#pragma unroll
                for (int t = 0; t < 7 - PAR; ++t) {
                    const int mt = kp - t;
                    if (mt >= 0 && mt <= 6)
                        acc[mt] = __builtin_amdgcn_mfma_f32_32x32x16_f16(a, bf[t], acc[mt], 0, 0, 0);
                }
            }
        }
    }

    __syncthreads();
    float* R = (float*)Tl;
    for (int ph = 0; ph < 4; ++ph) {
        if (w == ph) {
#pragma unroll
            for (int mt = 0; mt < 7; ++mt)
#pragma unroll
                for (int reg = 0; reg < 16; ++reg) {
                    int row = (reg & 3) + 8 * (reg >> 2) + 4 * oct;
                    int idx = (mt * 32 + row) * 32 + (l & 31);
                    float v = acc[mt][reg];
                    if (ph) v += R[idx];
                    R[idx] = v;
                }
        }
        __syncthreads();
    }
    float* P = Pp + (size_t)(PAR * 256 + b) * 7168;
    for (int i = tid; i < 7168; i += 256) P[i] = R[i];
}

__global__ __launch_bounds__(256, 2) void k_conv2m(const f16* __restrict__ Tpre,
                                                   const f16* __restrict__ Wb2,
                                                   float* __restrict__ Pp) {
    __shared__ f16 Tl[28 * 2 * 32 * 8];   // 28,672 B
    int bid = blockIdx.x;
    int b = bid >> 1;
    if (bid & 1) conv2m_body<1>(Tpre, Wb2, Pp, Tl, b);
    else         conv2m_body<0>(Tpre, Wb2, Pp, Tl, b);
}

// ------------------------------------------------------------------
// K3: sum 2 parity partials + maxpool + bias -> h2f
// ------------------------------------------------------------------
__global__ __launch_bounds__(256) void k_pool2(const float* __restrict__ Pp,
                                               const float* __restrict__ b2,
                                               float* __restrict__ h2f) {
    int b = blockIdx.x, tid = threadIdx.x;
    for (int idx = tid; idx < 1029; idx += 256) {
        int o = idx % 21; int r = idx / 21; int px = r % 7; int py = r / 7;
        float mx = -1e30f;
#pragma unroll
        for (int sy = 0; sy < 2; ++sy)
#pragma unroll
            for (int sx = 0; sx < 2; ++sx) {
                int py2 = 2 * py + sy, px2 = 2 * px + sx;
                int mt = py2 >> 1, rr = (py2 & 1) * 16 + px2;
                float v = Pp[(size_t)b * 7168 + (mt * 32 + rr) * 32 + o]
                        + Pp[(size_t)(256 + b) * 7168 + (mt * 32 + rr) * 32 + o];
                mx = fmaxf(mx, v);
            }
        h2f[(size_t)b * 1029 + o * 49 + py * 7 + px] = mx + b2[o];
    }
}

// ------------------------------------------------------------------
// K4: fk1 via MFMA (b64 staging).
// ------------------------------------------------------------------
__global__ __launch_bounds__(256) void k_fk1m(const float* __restrict__ h2f,
                                              const f16* __restrict__ Wf1b,
                                              float* __restrict__ P3) {
    __shared__ f16 A[26 * 32 * 32];
    const int bid = blockIdx.x;
    const int mt8 = bid / NCH, ks = bid % NCH;
    const int m0 = mt8 * 32, d0 = ks * 32;
    const int tid = threadIdx.x;
    {
        const int m = tid >> 3, dq = tid & 7;
        float c1v[4], ck[4], sk[4], ckm[4], skm[4];
        bool valid[4];
#pragma unroll
        for (int j = 0; j < 4; ++j) {
            int d = d0 + dq * 4 + j;
            valid[j] = d < 1029;
            float h = valid[j] ? h2f[(size_t)(m0 + m) * 1029 + d] : 0.f;
            float s1, c1; __sincosf(h, &s1, &c1);
            c1v[j] = c1;
            ck[j] = c1; sk[j] = s1; ckm[j] = 1.f; skm[j] = 0.f;
        }
#pragma unroll
        for (int g = 0; g < 13; ++g) {
            f16x4 vc, vs;
#pragma unroll
            for (int j = 0; j < 4; ++j) {
                vc[j] = valid[j] ? (f16)ck[j] : (f16)0;
                vs[j] = valid[j] ? (f16)sk[j] : (f16)0;
                float cn = 2.f * c1v[j] * ck[j] - ckm[j];
                float sn = 2.f * c1v[j] * sk[j] - skm[j];
                ckm[j] = ck[j]; ck[j] = cn; skm[j] = sk[j]; sk[j] = sn;
            }
            *(f16x4*)&A[g * 1024 + m * 32 + dq * 4] = vc;
            *(f16x4*)&A[(13 + g) * 1024 + m * 32 + dq * 4] = vs;
        }
    }
    __syncthreads();
    const int w = tid >> 6, l = tid & 63;
    const int mt = w >> 1, ntg = (w & 1) * 3;
    f32x4 acc[3] = {};
    for (int kstep = 0; kstep < 26; ++kstep) {
        f16x8 a = *(const f16x8*)&A[kstep * 1024 + (mt * 16 + (l & 15)) * 32 + (l >> 4) * 8];
#pragma unroll
        for (int j = 0; j < 3; ++j) {
            f16x8 bv = *(const f16x8*)&Wf1b[((((size_t)ks * 26 + kstep) * 6 + ntg + j) * 64 + l) * 8];
            acc[j] = __builtin_amdgcn_mfma_f32_16x16x32_f16(a, bv, acc[j], 0, 0, 0);
        }
    }
    const int o_base = (l & 15);
#pragma unroll
    for (int j = 0; j < 3; ++j) {
        int o = (ntg + j) * 16 + o_base;
        if (o < 89) {
#pragma unroll
            for (int jj = 0; jj < 4; ++jj) {
                int m = m0 + mt * 16 + (l >> 4) * 4 + jj;
                P3[((size_t)ks * 256 + m) * 89 + o] = acc[j][jj];
            }
        }
    }
}

// ------------------------------------------------------------------
// K5: reduce 33 fk1 partials + bias -> trig(G=8) -> fk2 -> f32 out
// ------------------------------------------------------------------
__global__ __launch_bounds__(128) void k_fk2(const float* __restrict__ P3,
                                             const float* __restrict__ bias1,
                                             const float* __restrict__ wf2,
                                             const float* __restrict__ bias2,
                                             float* __restrict__ out) {
    __shared__ float2 tcs2[89][8];
    __shared__ float part[80];
    int b = blockIdx.x, tid = threadIdx.x;
    if (tid < 89) {
        float v = bias1[tid];
        for (int ks = 0; ks < NCH; ++ks)
            v += P3[((size_t)ks * 256 + b) * 89 + tid];
#pragma unroll
        for (int g = 0; g < 8; ++g) {
            float s, c; __sincosf(v * (float)(g + 1), &s, &c);
            tcs2[tid][g] = make_float2(c, s);
        }
    }
    __syncthreads();
    if (tid < 80) {
        int o = tid >> 3, g = tid & 7;
        float s = 0.f;
        for (int d = 0; d < 89; ++d) {
            float2 tv = tcs2[d][g];
            s = fmaf(tv.x, wf2[((size_t)o * 89 + d) * 8 + g],
                fmaf(tv.y, wf2[7120 + ((size_t)o * 89 + d) * 8 + g], s));
        }
        part[tid] = s;
    }
    __syncthreads();
    if (tid < 10) {
        float v = bias2[tid];
#pragma unroll
        for (int g = 0; g < 8; ++g) v += part[tid * 8 + g];
        out[b * 10 + tid] = v;
    }
}

extern "C" void kernel_launch(void* const* d_in, const int* in_sizes, int n_in,
                              void* d_out, int out_size, void* d_ws, size_t ws_size,
                              hipStream_t stream) {
    const float* x   = (const float*)d_in[0];
    const float* w1  = (const float*)d_in[1];
    const float* b1  = (const float*)d_in[2];
    const float* w2  = (const float*)d_in[3];
    const float* b2  = (const float*)d_in[4];
    const float* wf1 = (const float*)d_in[5];
    const float* bf1 = (const float*)d_in[6];
    const float* wf2 = (const float*)d_in[7];
    const float* bf2v = (const float*)d_in[8];

    char* ws  = (char*)d_ws;
    f16*   Tpre = (f16*)(ws + TP_OFF);
    f16*   Wb2  = (f16*)(ws + WB_OFF);
    f16*   Wf1b = (f16*)(ws + WF_OFF);
    f16*   Wb1  = (f16*)(ws + W1_OFF);
    float* Pp   = (float*)(ws + PP_OFF);
    float* h2f  = (float*)(ws + H2_OFF);
    float* P3   = (float*)(ws + P3_OFF);

    k_front<<<695, 256, 0, stream>>>(w1, w2, wf1, Wb2, Wf1b, Wb1);
    k_conv1m<<<512, 256, 0, stream>>>(x, b1, Wb1, Tpre);
    k_conv2m<<<512, 256, 0, stream>>>(Tpre, Wb2, Pp);
    k_pool2<<<256, 256, 0, stream>>>(Pp, b2, h2f);
    k_fk1m<<<8 * NCH, 256, 0, stream>>>(h2f, Wf1b, P3);
    k_fk2<<<256, 128, 0, stream>>>(P3, bf1, wf2, bf2v, (float*)d_out);
}